// Round 8
// baseline (528.501 us; speedup 1.0000x reference)
//
#include <hip/hip_runtime.h>
#include <cstdint>
#include <cstddef>

#define E_DIM 1024
#define F_DIM 4096
#define S_LEN 2048
#define NB    4
#define NH    16
#define HD    64
#define MROWS 8192   // B*S

typedef __bf16 bf16x8 __attribute__((ext_vector_type(8)));
typedef float  f32x4  __attribute__((ext_vector_type(4)));

struct alignas(16) f4 { float x, y, z, w; };
__device__ __forceinline__ f4 ld4(const float* p){ return *(const f4*)p; }

__device__ __forceinline__ unsigned short f2bf(float f){
  union { float f; unsigned int u; } c; c.f = f;
  unsigned int u = c.u;
  return (unsigned short)((u + 0x7FFFu + ((u >> 16) & 1u)) >> 16);
}

// fast gelu: A&S 7.1.26 erf (|err|<=1.5e-7, below bf16 rounding of the output)
__device__ __forceinline__ float gelu_fast(float v){
  const float x  = v * 0.70710678118654752f;
  const float ax = fabsf(x);
  const float t  = __builtin_amdgcn_rcpf(1.0f + 0.3275911f * ax);
  const float p  = t*(0.254829592f + t*(-0.284496736f + t*(1.421413741f +
                   t*(-1.453152027f + t*1.061405429f))));
  float er = 1.0f - p * __expf(-x * x);
  er = (x < 0.0f) ? -er : er;
  return 0.5f * v * (1.0f + er);
}

// bijective XCD chunk-swizzle (grid must be %8)
__device__ __forceinline__ void xcd_swz(int gx, int gy, int& bn, int& bm){
  int fid = blockIdx.y * gx + blockIdx.x;
  const int nwg = gx * gy;
  fid = (fid & 7) * (nwg >> 3) + (fid >> 3);
  bn = fid % gx; bm = fid / gx;
}

// ---------------------------------------------------------------- cvt fp32->bf16 (optional scale)
__global__ void cvt_kernel(const float* __restrict__ in, unsigned short* __restrict__ out,
                           int n, float scale){
  int i = (blockIdx.x * 256 + threadIdx.x) * 4;
  if (i >= n) return;
  f4 f = ld4(in + i);
  ushort4 o;
  o.x = f2bf(f.x * scale); o.y = f2bf(f.y * scale);
  o.z = f2bf(f.z * scale); o.w = f2bf(f.w * scale);
  *(ushort4*)(out + i) = o;
}

// ---------------------------------------------------------------- bias concat (bq*qsc | bk | bv)
__global__ void bias_cat(const float* __restrict__ bq, const float* __restrict__ bk,
                         const float* __restrict__ bv, float* __restrict__ out, float qsc){
  int i = blockIdx.x * 256 + threadIdx.x;
  if (i >= 3 * E_DIM) return;
  float v = (i < E_DIM) ? bq[i] * qsc : (i < 2 * E_DIM ? bk[i - E_DIM] : bv[i - 2 * E_DIM]);
  out[i] = v;
}

// ---------------------------------------------------------------- LayerNorm (row=1024) -> bf16
__global__ __launch_bounds__(256) void ln_kernel(const float* __restrict__ in,
                                                 const float* __restrict__ g,
                                                 const float* __restrict__ b,
                                                 unsigned short* __restrict__ out){
  const int row = blockIdx.x;
  const int t = threadIdx.x;
  const float* xr = in + (size_t)row * E_DIM;
  f4 xv = ld4(xr + t * 4);
  float s  = xv.x + xv.y + xv.z + xv.w;
  float ss = xv.x*xv.x + xv.y*xv.y + xv.z*xv.z + xv.w*xv.w;
  #pragma unroll
  for (int o = 1; o < 64; o <<= 1){ s += __shfl_xor(s, o); ss += __shfl_xor(ss, o); }
  __shared__ float sa[4], sb[4];
  if ((t & 63) == 0){ sa[t >> 6] = s; sb[t >> 6] = ss; }
  __syncthreads();
  s  = sa[0] + sa[1] + sa[2] + sa[3];
  ss = sb[0] + sb[1] + sb[2] + sb[3];
  const float mean = s * (1.0f / E_DIM);
  const float var  = ss * (1.0f / E_DIM) - mean * mean;
  const float rstd = rsqrtf(var + 1e-5f);
  f4 gv = ld4(g + t * 4);
  f4 bv = ld4(b + t * 4);
  ushort4 o;
  o.x = f2bf((xv.x - mean) * rstd * gv.x + bv.x);
  o.y = f2bf((xv.y - mean) * rstd * gv.y + bv.y);
  o.z = f2bf((xv.z - mean) * rstd * gv.z + bv.z);
  o.w = f2bf((xv.w - mean) * rstd * gv.w + bv.w);
  *(ushort4*)(out + (size_t)row * E_DIM + t * 4) = o;
}

// ---------------------------------------------------------------- async global->LDS 16B
__device__ __forceinline__ void async_cp16(const unsigned short* g, unsigned short* l){
  __builtin_amdgcn_global_load_lds((const __attribute__((address_space(1))) unsigned int*)g,
                                   (__attribute__((address_space(3)))       unsigned int*)l,
                                   16, 0, 0);
}

#define VMW4() asm volatile("s_waitcnt vmcnt(4)" ::: "memory")
#define VMW0() asm volatile("s_waitcnt vmcnt(0)" ::: "memory")
#define BAR()  __builtin_amdgcn_s_barrier()

// ---------------------------------------------------------------- GEMM 256x256, 8-phase + EARLY READS (R6-proven; QKV/FFN1)
template<int EPI>
__global__ __launch_bounds__(512, 2) void gemm256(const unsigned short* __restrict__ A,
                                                  const unsigned short* __restrict__ W,
                                                  const float* __restrict__ bias,
                                                  unsigned short* __restrict__ outp,
                                                  int M, int N, int K){
  __shared__ unsigned short lds[2][2][256 * 64];   // [buf][A=0/B=1][row*64+col] = 128 KiB
  const int bn = blockIdx.x, bm = blockIdx.y;
  const int tid = threadIdx.x;
  const int lane = tid & 63;
  const int wv = tid >> 6;
  const int lr = lane & 15, qd = lane >> 4;
  const int wm = wv >> 2, wn = wv & 3;
  const int NT = K >> 6;

  f32x4 acc[2][2][4][2];
  #pragma unroll
  for (int a = 0; a < 2; ++a)
    #pragma unroll
    for (int b = 0; b < 2; ++b)
      #pragma unroll
      for (int c = 0; c < 4; ++c)
        #pragma unroll
        for (int d = 0; d < 2; ++d)
          acc[a][b][c][d] = f32x4{0.f, 0.f, 0.f, 0.f};

  const int srow = tid >> 3;
  const int scol = ((tid & 7) ^ (srow & 7)) * 8;
  const unsigned short* Ab = A + (size_t)(bm * 256 + srow) * K + scol;
  const unsigned short* Wb = W + (size_t)(bn * 256 + srow) * K + scol;

#define STAGE_A(bufi, h, kt) do{ \
    async_cp16(Ab + (size_t)((h)*128     ) * K + (size_t)(kt) * 64, &lds[bufi][0][((h)*128     ) * 64 + tid * 8]); \
    async_cp16(Ab + (size_t)((h)*128 + 64) * K + (size_t)(kt) * 64, &lds[bufi][0][((h)*128 + 64) * 64 + tid * 8]); \
  }while(0)
#define STAGE_B(bufi, h, kt) do{ \
    async_cp16(Wb + (size_t)((h)*128     ) * K + (size_t)(kt) * 64, &lds[bufi][1][((h)*128     ) * 64 + tid * 8]); \
    async_cp16(Wb + (size_t)((h)*128 + 64) * K + (size_t)(kt) * 64, &lds[bufi][1][((h)*128 + 64) * 64 + tid * 8]); \
  }while(0)

  const int sw0 = ((qd    ) ^ (lr & 7)) * 8;
  const int sw1 = ((qd + 4) ^ (lr & 7)) * 8;
  const int arow = wm * 64 + lr;
  const int brow = wn * 32 + lr;

  bf16x8 af[4][2], b0[2][2], b1[2][2];

#define LDA(bufi, mh) do{ \
    _Pragma("unroll") \
    for (int mt = 0; mt < 4; ++mt){ \
      const int r_ = (mh)*128 + arow + mt * 16; \
      af[mt][0] = *(const bf16x8*)&lds[bufi][0][r_ * 64 + sw0]; \
      af[mt][1] = *(const bf16x8*)&lds[bufi][0][r_ * 64 + sw1]; \
    } }while(0)
#define LDB(bufi, nh, dst) do{ \
    _Pragma("unroll") \
    for (int nt = 0; nt < 2; ++nt){ \
      const int r_ = (nh)*128 + brow + nt * 16; \
      dst[nt][0] = *(const bf16x8*)&lds[bufi][1][r_ * 64 + sw0]; \
      dst[nt][1] = *(const bf16x8*)&lds[bufi][1][r_ * 64 + sw1]; \
    } }while(0)
#define MMA(mh, nh, bfr) do{ \
    __builtin_amdgcn_s_setprio(1); \
    _Pragma("unroll") \
    for (int kk = 0; kk < 2; ++kk) \
      _Pragma("unroll") \
      for (int mt = 0; mt < 4; ++mt) \
        _Pragma("unroll") \
        for (int nt = 0; nt < 2; ++nt) \
          acc[mh][nh][mt][nt] = __builtin_amdgcn_mfma_f32_16x16x32_bf16(af[mt][kk], bfr[nt][kk], acc[mh][nh][mt][nt], 0, 0, 0); \
    __builtin_amdgcn_s_setprio(0); \
  }while(0)

  STAGE_A(0, 0, 0); STAGE_B(0, 1, 0); STAGE_A(0, 1, 0); STAGE_B(0, 0, 0);
  STAGE_A(1, 0, 1); STAGE_B(1, 1, 1);
  VMW4(); BAR();

  for (int t = 0; t < NT; t += 2){
    const bool s2 = (t + 2) < NT, s3 = (t + 3) < NT;
    LDA(0, 0); LDB(0, 0, b0);
    STAGE_A(1, 1, t + 1);
    BAR(); MMA(0, 0, b0);
    LDB(0, 1, b1);
    BAR();
    STAGE_B(1, 0, t + 1);
    BAR(); MMA(0, 1, b1);
    LDA(0, 1);
    BAR();
    if (s2) STAGE_A(0, 0, t + 2);
    BAR(); MMA(1, 1, b1); BAR();
    if (s2) STAGE_B(0, 1, t + 2);
    BAR(); MMA(1, 0, b0);
    if (s2) { VMW4(); } else { VMW0(); }
    LDA(1, 0);
    BAR();
    LDB(1, 0, b0);
    if (s2) STAGE_A(0, 1, t + 2);
    BAR(); MMA(0, 0, b0);
    LDB(1, 1, b1);
    BAR();
    if (s2) STAGE_B(0, 0, t + 2);
    BAR(); MMA(0, 1, b1);
    LDA(1, 1);
    BAR();
    if (s3) STAGE_A(1, 0, t + 3);
    BAR(); MMA(1, 1, b1); BAR();
    if (s3) STAGE_B(1, 1, t + 3);
    BAR(); MMA(1, 0, b0);
    VMW4();
    BAR();
  }

  #pragma unroll
  for (int mh = 0; mh < 2; ++mh)
    #pragma unroll
    for (int nh = 0; nh < 2; ++nh)
      #pragma unroll
      for (int mt = 0; mt < 4; ++mt){
        const int gm0 = bm * 256 + mh * 128 + wm * 64 + mt * 16 + qd * 4;
        #pragma unroll
        for (int r = 0; r < 4; ++r){
          const size_t rowoff = (size_t)(gm0 + r) * N;
          #pragma unroll
          for (int nt = 0; nt < 2; ++nt){
            const int gn = bn * 256 + nh * 128 + wn * 32 + nt * 16 + lr;
            float v = acc[mh][nh][mt][nt][r] + bias[gn];
            if constexpr (EPI == 1) v = gelu_fast(v);
            outp[rowoff + gn] = f2bf(v);
          }
        }
      }
#undef STAGE_A
#undef STAGE_B
#undef LDA
#undef LDB
#undef MMA
}

// ---------------------------------------------------------------- GEMM 256x128, 4-phase early-read (Wo/FFN2, N=1024)
// BM=256 BN=128 BK=64; grid (N/128, M/256) = 256 blocks = 1/CU. 8 waves 4Mx2N,
// wave owns 64x64 (acc[4][4]). Per 2-K-tile iteration, 4 phases; B split into
// nt-halves c0 (b0: nt 0,1) / c1 (b1: nt 2,3); af[4][2] shared by both.
// Stage schedule: p0:B(t+1->buf1)[2] p1:A(t+2->buf0)[4] p2:B(t+2->buf0)[2]
// p3:A(t+3->buf1)[4]; vmcnt(4) at p1 (certifies A(t+1)+B(t+1) before buf1
// early-reads) and p3 (certifies tile t+2 before next boundary reads).
// Hazards (verified): each stage targets a region whose last ds_read delivered
// >=1 barrier earlier; every read's data certified by the preceding vmcnt+BAR.
// EPI2: out fp32 = acc + bias + res. Numerics identical to gemm_bt (same
// K-tile/kk summation order).
__global__ __launch_bounds__(512, 1) void gemm256x128(const unsigned short* __restrict__ A,
                                                      const unsigned short* __restrict__ W,
                                                      const float* __restrict__ bias,
                                                      const float* __restrict__ res,
                                                      float* __restrict__ outp,
                                                      int M, int N, int K){
  __shared__ unsigned short As[2][256 * 64];   // 64 KB
  __shared__ unsigned short Bs[2][128 * 64];   // 32 KB
  int bn, bm; xcd_swz(gridDim.x, gridDim.y, bn, bm);
  const int tid = threadIdx.x;
  const int lane = tid & 63;
  const int wv = tid >> 6;
  const int lr = lane & 15, qd = lane >> 4;
  const int wm = wv >> 1, wn = wv & 1;         // 4M x 2N
  const int NT = K >> 6;                       // even (K=1024/4096)

  f32x4 acc[4][4];
  #pragma unroll
  for (int a = 0; a < 4; ++a)
    #pragma unroll
    for (int b = 0; b < 4; ++b)
      acc[a][b] = f32x4{0.f, 0.f, 0.f, 0.f};

  const int srow = tid >> 3;                   // 0..63
  const int scol = ((tid & 7) ^ (srow & 7)) * 8;
  const int sdst = srow * 64 + (tid & 7) * 8;
  const unsigned short* Ab = A + (size_t)(bm * 256 + srow) * K + scol;
  const unsigned short* Wb = W + (size_t)(bn * 128 + srow) * K + scol;

#define XSTAGE_A(bufi, kt) do{ \
    _Pragma("unroll") \
    for (int h = 0; h < 4; ++h) \
      async_cp16(Ab + (size_t)(h * 64) * K + (size_t)(kt) * 64, &As[bufi][h * 64 * 64 + sdst]); \
  }while(0)
#define XSTAGE_B(bufi, kt) do{ \
    _Pragma("unroll") \
    for (int h = 0; h < 2; ++h) \
      async_cp16(Wb + (size_t)(h * 64) * K + (size_t)(kt) * 64, &Bs[bufi][h * 64 * 64 + sdst]); \
  }while(0)

  const int sw0 = ((qd    ) ^ (lr & 7)) * 8;
  const int sw1 = ((qd + 4) ^ (lr & 7)) * 8;
  const int arow = wm * 64 + lr;
  const int brow = wn * 64 + lr;

  bf16x8 af[4][2], b0[2][2], b1[2][2];

#define XLDA(bufi) do{ \
    _Pragma("unroll") \
    for (int mt = 0; mt < 4; ++mt){ \
      const int r_ = arow + mt * 16; \
      af[mt][0] = *(const bf16x8*)&As[bufi][r_ * 64 + sw0]; \
      af[mt][1] = *(const bf16x8*)&As[bufi][r_ * 64 + sw1]; \
    } }while(0)
#define XLDB0(bufi) do{ \
    _Pragma("unroll") \
    for (int j = 0; j < 2; ++j){ \
      const int r_ = brow + j * 16; \
      b0[j][0] = *(const bf16x8*)&Bs[bufi][r_ * 64 + sw0]; \
      b0[j][1] = *(const bf16x8*)&Bs[bufi][r_ * 64 + sw1]; \
    } }while(0)
#define XLDB1(bufi) do{ \
    _Pragma("unroll") \
    for (int j = 0; j < 2; ++j){ \
      const int r_ = brow + (2 + j) * 16; \
      b1[j][0] = *(const bf16x8*)&Bs[bufi][r_ * 64 + sw0]; \
      b1[j][1] = *(const bf16x8*)&Bs[bufi][r_ * 64 + sw1]; \
    } }while(0)
#define XMMA0() do{ \
    __builtin_amdgcn_s_setprio(1); \
    _Pragma("unroll") \
    for (int kk = 0; kk < 2; ++kk) \
      _Pragma("unroll") \
      for (int mt = 0; mt < 4; ++mt) \
        _Pragma("unroll") \
        for (int j = 0; j < 2; ++j) \
          acc[mt][j] = __builtin_amdgcn_mfma_f32_16x16x32_bf16(af[mt][kk], b0[j][kk], acc[mt][j], 0, 0, 0); \
    __builtin_amdgcn_s_setprio(0); \
  }while(0)
#define XMMA1() do{ \
    __builtin_amdgcn_s_setprio(1); \
    _Pragma("unroll") \
    for (int kk = 0; kk < 2; ++kk) \
      _Pragma("unroll") \
      for (int mt = 0; mt < 4; ++mt) \
        _Pragma("unroll") \
        for (int j = 0; j < 2; ++j) \
          acc[mt][2 + j] = __builtin_amdgcn_mfma_f32_16x16x32_bf16(af[mt][kk], b1[j][kk], acc[mt][2 + j], 0, 0, 0); \
    __builtin_amdgcn_s_setprio(0); \
  }while(0)

  // prologue: A(t0),B(t0)->buf0 [6], A(t1)->buf1 [4]; certify t0 (t1's A in flight)
  XSTAGE_A(0, 0); XSTAGE_B(0, 0); XSTAGE_A(1, 1);
  VMW4(); BAR();

  for (int t = 0; t < NT; t += 2){
    const bool s2 = (t + 2) < NT;
    // p0: boundary reads (buf0 certified by prev p3 vmcnt+BAR / prologue)
    XLDA(0); XLDB0(0);
    XSTAGE_B(1, t + 1);                    // [2] buf1.B free since prev p2-read
    BAR(); XMMA0();
    XLDB1(0);                              // early: b1 for p1
    BAR();
    // p1
    if (s2) XSTAGE_A(0, t + 2);            // [4] buf0.A consumed at p0
    BAR(); XMMA1();
    if (s2) { VMW4(); } else { VMW0(); }   // certify A(t+1)+B(t+1)
    XLDA(1); XLDB0(1);                     // early: af,b0 for p2 (buf1)
    BAR();
    // p2
    if (s2) XSTAGE_B(0, t + 2);            // [2] buf0.B consumed at p1
    BAR(); XMMA0();
    XLDB1(1);                              // early: b1 for p3
    BAR();
    // p3
    if (s2) XSTAGE_A(1, t + 3);            // [4] buf1.A consumed at p2
    BAR(); XMMA1();
    if (s2) VMW4();                        // certify tile t+2 for next p0
    BAR();
  }

  // epilogue: fp32 out = acc + bias + res
  #pragma unroll
  for (int mt = 0; mt < 4; ++mt){
    #pragma unroll
    for (int r = 0; r < 4; ++r){
      const int gm = bm * 256 + wm * 64 + mt * 16 + qd * 4 + r;
      const size_t rowoff = (size_t)gm * N;
      #pragma unroll
      for (int nt = 0; nt < 4; ++nt){
        const int gn = bn * 128 + wn * 64 + nt * 16 + lr;
        const float v = acc[mt][nt][r] + bias[gn];
        outp[rowoff + gn] = v + res[rowoff + gn];
      }
    }
  }
#undef XSTAGE_A
#undef XSTAGE_B
#undef XLDA
#undef XLDB0
#undef XLDB1
#undef XMMA0
#undef XMMA1
}

// ---------------------------------------------------------------- V transpose: qkv[tok][2048+h*64+d] -> Vt[(b,h,d)][tok]
__global__ __launch_bounds__(256) void vtrans(const unsigned short* __restrict__ QKV,
                                              unsigned short* __restrict__ Vt){
  __shared__ unsigned short Ts[64 * 66];
  const int st = blockIdx.x;               // s-tile 0..31
  const int h = blockIdx.y, b = blockIdx.z;
  const int tid = threadIdx.x;
  const size_t srcbase = (size_t)(b * S_LEN + st * 64) * 3072 + 2 * E_DIM + h * HD;
  #pragma unroll
  for (int it = 0; it < 4; ++it){
    const int ch = tid + it * 256;
    const int row = ch >> 4, c4 = (ch & 15) * 4;
    *(ushort4*)&Ts[row * 66 + c4] = *(const ushort4*)(QKV + srcbase + (size_t)row * 3072 + c4);
  }
  __syncthreads();
  const size_t dstbase = (size_t)((b * NH + h) * HD) * S_LEN + st * 64;
  #pragma unroll
  for (int it = 0; it < 4; ++it){
    const int ch = tid + it * 256;
    const int d = ch >> 4, t4 = (ch & 15) * 4;
    ushort4 o;
    o.x = Ts[(t4 + 0) * 66 + d];
    o.y = Ts[(t4 + 1) * 66 + d];
    o.z = Ts[(t4 + 2) * 66 + d];
    o.w = Ts[(t4 + 3) * 66 + d];
    *(ushort4*)&Vt[dstbase + (size_t)d * S_LEN + t4] = o;
  }
}

// ---------------------------------------------------------------- MFMA flash attention, no-max softmax (R7-proven)
#define AST 72   // Ps stride only
__global__ __launch_bounds__(256) void attn_mfma(const unsigned short* __restrict__ QKV,
                                                 const unsigned short* __restrict__ Vt,
                                                 unsigned short* __restrict__ Om){
  __shared__ unsigned short Ks[64 * 64];    // K[key][d], XOR-chunk layout
  __shared__ unsigned short Vs[64 * 64];    // V^T[d][key], XOR-chunk layout
  __shared__ unsigned short Ps[64 * AST];   // P[q][key], per-wave 16-row slices
  const int pairi = blockIdx.x;             // 0..15
  const int h = blockIdx.y, b = blockIdx.z;
  const int tid = threadIdx.x;
  const int w = tid >> 6, lane = tid & 63;
  const int lr = lane & 15, qd = lane >> 4;
  const size_t row0 = (size_t)b * S_LEN;
  const int qcol = h * HD;
  const int kcol = E_DIM + h * HD;
  const unsigned short* Vtb = Vt + (size_t)((b * NH + h) * HD) * S_LEN;

  const int sr  = tid >> 3;                         // 0..31
  const int sc  = (((tid & 7) ^ (sr & 7))) * 8;     // source col offset (ushorts)
  const int sdst = sr * 64 + (tid & 7) * 8;         // LDS dest (ushorts)

  bf16x8 ones;
  #pragma unroll
  for (int j = 0; j < 8; ++j) ones[j] = (__bf16)1.0f;

  for (int ph = 0; ph < 2; ++ph){
    const int qb_t = ph ? (31 - pairi) : pairi;
    const int q0 = qb_t * 64 + w * 16;

    bf16x8 qf[2];
    #pragma unroll
    for (int kk = 0; kk < 2; ++kk)
      qf[kk] = *(const bf16x8*)(QKV + (row0 + q0 + lr) * 3072 + qcol + kk * 32 + qd * 8);

    f32x4 accd[4];
    #pragma unroll
    for (int dt = 0; dt < 4; ++dt) accd[dt] = f32x4{0.f, 0.f, 0.f, 0.f};
    f32x4 lacc = f32x4{0.f, 0.f, 0.f, 0.f};

    uint4 k0r = *(const uint4*)(QKV + (row0 + sr) * 3072 + kcol + sc);
    uint4 k1r = *(const uint4*)(QKV + (row0 + sr + 32) * 3072 + kcol + sc);
    uint4 v0r = *(const uint4*)(Vtb + (size_t)sr * S_LEN + sc);
    uint4 v1r = *(const uint4*)(Vtb + (size_t)(sr + 32) * S_LEN + sc);

    for (int kt = 0; kt <= qb_t; ++kt){
      __syncthreads();
      *(uint4*)&Ks[sdst          ] = k0r;
      *(uint4*)&Ks[sdst + 32 * 64] = k1r;
      *(uint4*)&Vs[sdst          ] = v0r;
      *(uint4*)&Vs[sdst + 32 * 64] = v1r;
      if (kt < qb_t){
        const int kn = kt + 1;
        k0r = *(const uint4*)(QKV + (row0 + kn * 64 + sr) * 3072 + kcol + sc);
        k1r = *(const uint4*)(QKV + (row0 + kn * 64 + sr + 32) * 3072 + kcol + sc);
        v0r = *(const uint4*)(Vtb + (size_t)sr * S_LEN + kn * 64 + sc);
        v1r = *(const uint4*)(Vtb + (size_t)(sr + 32) * S_LEN + kn * 64 + sc);
      }
      __syncthreads();

      f32x4 s[4];
      #pragma unroll
      for (int nt = 0; nt < 4; ++nt) s[nt] = f32x4{0.f, 0.f, 0.f, 0.f};
      #pragma unroll
      for (int kk = 0; kk < 2; ++kk){
        bf16x8 kf[4];
        #pragma unroll
        for (int nt = 0; nt < 4; ++nt)
          kf[nt] = *(const bf16x8*)&Ks[(nt * 16 + lr) * 64 + (((kk * 4 + qd) ^ (lr & 7))) * 8];
        #pragma unroll
        for (int nt = 0; nt < 4; ++nt)
          s[nt] = __builtin_amdgcn_mfma_f32_16x16x32_bf16(qf[kk], kf[nt], s[nt], 0, 0, 0);
      }
      if (kt == qb_t){
        #pragma unroll
        for (int nt = 0; nt < 4; ++nt)
          #pragma unroll
          for (int r = 0; r < 4; ++r){
            const int q  = q0 + qd * 4 + r;
            const int ky = kt * 64 + nt * 16 + lr;
            if (ky > q) s[nt][r] = -3e38f;
          }
      }
      #pragma unroll
      for (int nt = 0; nt < 4; ++nt)
        #pragma unroll
        for (int r = 0; r < 4; ++r){
          union { float f; unsigned u; } cc;
          cc.f = exp2f(s[nt][r]);
          Ps[(w * 16 + qd * 4 + r) * AST + nt * 16 + lr] = (unsigned short)((cc.u + 0x8000u) >> 16);
        }
      __builtin_amdgcn_s_waitcnt(0xc07f);   // lgkmcnt(0)
      #pragma unroll
      for (int kk = 0; kk < 2; ++kk){
        bf16x8 pf = *(const bf16x8*)&Ps[(w * 16 + lr) * AST + kk * 32 + qd * 8];
        bf16x8 vf[4];
        #pragma unroll
        for (int dt = 0; dt < 4; ++dt)
          vf[dt] = *(const bf16x8*)&Vs[(dt * 16 + lr) * 64 + (((kk * 4 + qd) ^ (lr & 7))) * 8];
        #pragma unroll
        for (int dt = 0; dt < 4; ++dt)
          accd[dt] = __builtin_amdgcn_mfma_f32_16x16x32_bf16(pf, vf[dt], accd[dt], 0, 0, 0);
        lacc = __builtin_amdgcn_mfma_f32_16x16x32_bf16(pf, ones, lacc, 0, 0, 0);
      }
    }

    #pragma unroll
    for (int r = 0; r < 4; ++r){
      const float inv = 1.0f / lacc[r];
      const size_t ro = (row0 + q0 + qd * 4 + r) * E_DIM + qcol;
      #pragma unroll
      for (int dt = 0; dt < 4; ++dt)
        Om[ro + dt * 16 + lr] = f2bf(accd[dt][r] * inv);
    }
  }
}

// ---------------------------------------------------------------- launch
extern "C" void kernel_launch(void* const* d_in, const int* in_sizes, int n_in,
                              void* d_out, int out_size, void* d_ws, size_t ws_size,
                              hipStream_t stream){
  const float* x    = (const float*)d_in[0];
  const float* ln1g = (const float*)d_in[2];
  const float* ln1b = (const float*)d_in[3];
  const float* Wq   = (const float*)d_in[4];
  const float* bq   = (const float*)d_in[5];
  const float* Wk   = (const float*)d_in[6];
  const float* bk   = (const float*)d_in[7];
  const float* Wv   = (const float*)d_in[8];
  const float* bv   = (const float*)d_in[9];
  const float* Wo   = (const float*)d_in[10];
  const float* bo   = (const float*)d_in[11];
  const float* ln2g = (const float*)d_in[12];
  const float* ln2b = (const float*)d_in[13];
  const float* W1   = (const float*)d_in[14];
  const float* b1   = (const float*)d_in[15];
  const float* W2   = (const float*)d_in[16];
  const float* b2   = (const float*)d_in[17];

  char* ws = (char*)d_ws;
  const size_t MB = 1024 * 1024;
  unsigned short* Wqkv_b = (unsigned short*)(ws + 0 * MB);   // 6 MB (Wq|Wk|Wv)
  unsigned short* Wo_b   = (unsigned short*)(ws + 6 * MB);   // 2 MB
  unsigned short* W1_b   = (unsigned short*)(ws + 8 * MB);   // 8 MB
  unsigned short* W2_b   = (unsigned short*)(ws + 16 * MB);  // 8 MB
  unsigned short* qkvb   = (unsigned short*)(ws + 24 * MB);  // 48 MB [8192][3072]
  float*          bqkv   = (float*)(ws + 72 * MB);           // 12 KB (dead after QKV gemm)
  unsigned short* Vt_g   = (unsigned short*)(ws + 72 * MB);  // 16 MB (overwrites bqkv after use)
  unsigned short* lnb    = (unsigned short*)(ws + 88 * MB);  // 16 MB (ln out / attn ctx, reused)
  float*          xres   = (float*)(ws + 104 * MB);          // 32 MB
  unsigned short* ffn1   = (unsigned short*)(ws + 24 * MB);  // 64 MB, aliases qkvb+Vt (dead by then)
  unsigned short* ctxb   = lnb;                              // attn ctx shares lnb

  const float QSC = 0.125f * 1.4426950408889634f;            // 1/sqrt(D) * log2(e)

  cvt_kernel<<<1024, 256, 0, stream>>>(Wq, Wqkv_b,                   E_DIM * E_DIM, QSC);
  cvt_kernel<<<1024, 256, 0, stream>>>(Wk, Wqkv_b + E_DIM * E_DIM,   E_DIM * E_DIM, 1.0f);
  cvt_kernel<<<1024, 256, 0, stream>>>(Wv, Wqkv_b + 2 * E_DIM * E_DIM, E_DIM * E_DIM, 1.0f);
  cvt_kernel<<<1024, 256, 0, stream>>>(Wo, Wo_b, E_DIM * E_DIM, 1.0f);
  cvt_kernel<<<4096, 256, 0, stream>>>(W1, W1_b, F_DIM * E_DIM, 1.0f);
  cvt_kernel<<<4096, 256, 0, stream>>>(W2, W2_b, F_DIM * E_DIM, 1.0f);
  bias_cat<<<12, 256, 0, stream>>>(bq, bk, bv, bqkv, QSC);

  ln_kernel<<<MROWS, 256, 0, stream>>>(x, ln1g, ln1b, lnb);

  // fused QKV GEMM: [8192,1024] @ [3072,1024]^T -> [8192,3072]  (256^2 early-read)
  gemm256<0><<<dim3(3 * E_DIM / 256, MROWS / 256), 512, 0, stream>>>(
      lnb, Wqkv_b, bqkv, qkvb, MROWS, 3 * E_DIM, E_DIM);

  vtrans<<<dim3(S_LEN / 64, NH, NB), 256, 0, stream>>>(qkvb, Vt_g);

  attn_mfma<<<dim3(16, NH, NB), 256, 0, stream>>>(qkvb, Vt_g, ctxb);

  // Wo: [8192,1024] @ [1024,1024]^T + x -> xres (fp32)  (256x128 4-phase)
  gemm256x128<<<dim3(E_DIM / 128, MROWS / 256), 512, 0, stream>>>(
      ctxb, Wo_b, bo, x, xres, MROWS, E_DIM, E_DIM);

  ln_kernel<<<MROWS, 256, 0, stream>>>(xres, ln2g, ln2b, lnb);

  // FFN1: [8192,1024] @ [4096,1024]^T -> gelu -> [8192,4096]  (256^2 early-read)
  gemm256<1><<<dim3(F_DIM / 256, MROWS / 256), 512, 0, stream>>>(
      lnb, W1_b, b1, ffn1, MROWS, F_DIM, E_DIM);

  // FFN2: [8192,4096] @ [1024,4096]^T + xres -> out (fp32)  (256x128 4-phase)
  gemm256x128<<<dim3(E_DIM / 128, MROWS / 256), 512, 0, stream>>>(
      ffn1, W2_b, b2, xres, (float*)d_out, MROWS, E_DIM, F_DIM);
}

// Round 9
// 502.243 us; speedup vs baseline: 1.0523x; 1.0523x over previous
//
#include <hip/hip_runtime.h>
#include <cstdint>
#include <cstddef>

#define E_DIM 1024
#define F_DIM 4096
#define S_LEN 2048
#define NB    4
#define NH    16
#define HD    64
#define MROWS 8192   // B*S

typedef __bf16 bf16x8 __attribute__((ext_vector_type(8)));
typedef float  f32x4  __attribute__((ext_vector_type(4)));

struct alignas(16) f4 { float x, y, z, w; };
__device__ __forceinline__ f4 ld4(const float* p){ return *(const f4*)p; }

__device__ __forceinline__ unsigned short f2bf(float f){
  union { float f; unsigned int u; } c; c.f = f;
  unsigned int u = c.u;
  return (unsigned short)((u + 0x7FFFu + ((u >> 16) & 1u)) >> 16);
}

// fast gelu: A&S 7.1.26 erf (|err|<=1.5e-7, below bf16 rounding of the output)
__device__ __forceinline__ float gelu_fast(float v){
  const float x  = v * 0.70710678118654752f;
  const float ax = fabsf(x);
  const float t  = __builtin_amdgcn_rcpf(1.0f + 0.3275911f * ax);
  const float p  = t*(0.254829592f + t*(-0.284496736f + t*(1.421413741f +
                   t*(-1.453152027f + t*1.061405429f))));
  float er = 1.0f - p * __expf(-x * x);
  er = (x < 0.0f) ? -er : er;
  return 0.5f * v * (1.0f + er);
}

// bijective XCD chunk-swizzle (grid must be %8)
__device__ __forceinline__ void xcd_swz(int gx, int gy, int& bn, int& bm){
  int fid = blockIdx.y * gx + blockIdx.x;
  const int nwg = gx * gy;
  fid = (fid & 7) * (nwg >> 3) + (fid >> 3);
  bn = fid % gx; bm = fid / gx;
}

// ---------------------------------------------------------------- fused weight cvt + bias concat (1 launch)
// blocks [0,12288): fp32->bf16 x4/thread over {Wq*qsc|Wk|Wv|Wo|W1|W2};
// blocks [12288,12300): bias concat (bq*qsc | bk | bv) fp32.
__global__ void cvt_all(const float* __restrict__ Wq, const float* __restrict__ Wk,
                        const float* __restrict__ Wv, const float* __restrict__ Wo,
                        const float* __restrict__ W1, const float* __restrict__ W2,
                        const float* __restrict__ bq, const float* __restrict__ bk,
                        const float* __restrict__ bv,
                        unsigned short* __restrict__ Wqkv_b, unsigned short* __restrict__ Wo_b,
                        unsigned short* __restrict__ W1_b, unsigned short* __restrict__ W2_b,
                        float* __restrict__ bqkv, float qsc){
  const int blk = blockIdx.x;
  if (blk < 12288){
    const float* src; unsigned short* dst; float scale = 1.0f; int base;
    if      (blk < 1024){ src = Wq; dst = Wqkv_b;                 base = blk;        scale = qsc; }
    else if (blk < 2048){ src = Wk; dst = Wqkv_b + 1024 * 1024;   base = blk - 1024; }
    else if (blk < 3072){ src = Wv; dst = Wqkv_b + 2048 * 1024;   base = blk - 2048; }
    else if (blk < 4096){ src = Wo; dst = Wo_b;                   base = blk - 3072; }
    else if (blk < 8192){ src = W1; dst = W1_b;                   base = blk - 4096; }
    else                { src = W2; dst = W2_b;                   base = blk - 8192; }
    const int i = (base * 256 + threadIdx.x) * 4;
    f4 f = ld4(src + i);
    ushort4 o;
    o.x = f2bf(f.x * scale); o.y = f2bf(f.y * scale);
    o.z = f2bf(f.z * scale); o.w = f2bf(f.w * scale);
    *(ushort4*)(dst + i) = o;
  } else {
    const int i = (blk - 12288) * 256 + threadIdx.x;
    if (i < 3 * E_DIM){
      float v = (i < E_DIM) ? bq[i] * qsc : (i < 2 * E_DIM ? bk[i - E_DIM] : bv[i - 2 * E_DIM]);
      bqkv[i] = v;
    }
  }
}

// ---------------------------------------------------------------- LayerNorm (row=1024) -> bf16
__global__ __launch_bounds__(256) void ln_kernel(const float* __restrict__ in,
                                                 const float* __restrict__ g,
                                                 const float* __restrict__ b,
                                                 unsigned short* __restrict__ out){
  const int row = blockIdx.x;
  const int t = threadIdx.x;
  const float* xr = in + (size_t)row * E_DIM;
  f4 xv = ld4(xr + t * 4);
  float s  = xv.x + xv.y + xv.z + xv.w;
  float ss = xv.x*xv.x + xv.y*xv.y + xv.z*xv.z + xv.w*xv.w;
  #pragma unroll
  for (int o = 1; o < 64; o <<= 1){ s += __shfl_xor(s, o); ss += __shfl_xor(ss, o); }
  __shared__ float sa[4], sb[4];
  if ((t & 63) == 0){ sa[t >> 6] = s; sb[t >> 6] = ss; }
  __syncthreads();
  s  = sa[0] + sa[1] + sa[2] + sa[3];
  ss = sb[0] + sb[1] + sb[2] + sb[3];
  const float mean = s * (1.0f / E_DIM);
  const float var  = ss * (1.0f / E_DIM) - mean * mean;
  const float rstd = rsqrtf(var + 1e-5f);
  f4 gv = ld4(g + t * 4);
  f4 bv = ld4(b + t * 4);
  ushort4 o;
  o.x = f2bf((xv.x - mean) * rstd * gv.x + bv.x);
  o.y = f2bf((xv.y - mean) * rstd * gv.y + bv.y);
  o.z = f2bf((xv.z - mean) * rstd * gv.z + bv.z);
  o.w = f2bf((xv.w - mean) * rstd * gv.w + bv.w);
  *(ushort4*)(out + (size_t)row * E_DIM + t * 4) = o;
}

// ---------------------------------------------------------------- async global->LDS 16B
__device__ __forceinline__ void async_cp16(const unsigned short* g, unsigned short* l){
  __builtin_amdgcn_global_load_lds((const __attribute__((address_space(1))) unsigned int*)g,
                                   (__attribute__((address_space(3)))       unsigned int*)l,
                                   16, 0, 0);
}

#define VMW4() asm volatile("s_waitcnt vmcnt(4)" ::: "memory")
#define VMW0() asm volatile("s_waitcnt vmcnt(0)" ::: "memory")
#define BAR()  __builtin_amdgcn_s_barrier()

// ---------------------------------------------------------------- GEMM 256x256, 8-phase + EARLY READS (R6-proven; QKV/FFN1)
template<int EPI>
__global__ __launch_bounds__(512, 2) void gemm256(const unsigned short* __restrict__ A,
                                                  const unsigned short* __restrict__ W,
                                                  const float* __restrict__ bias,
                                                  unsigned short* __restrict__ outp,
                                                  int M, int N, int K){
  __shared__ unsigned short lds[2][2][256 * 64];   // [buf][A=0/B=1][row*64+col] = 128 KiB
  const int bn = blockIdx.x, bm = blockIdx.y;
  const int tid = threadIdx.x;
  const int lane = tid & 63;
  const int wv = tid >> 6;
  const int lr = lane & 15, qd = lane >> 4;
  const int wm = wv >> 2, wn = wv & 3;
  const int NT = K >> 6;

  f32x4 acc[2][2][4][2];
  #pragma unroll
  for (int a = 0; a < 2; ++a)
    #pragma unroll
    for (int b = 0; b < 2; ++b)
      #pragma unroll
      for (int c = 0; c < 4; ++c)
        #pragma unroll
        for (int d = 0; d < 2; ++d)
          acc[a][b][c][d] = f32x4{0.f, 0.f, 0.f, 0.f};

  const int srow = tid >> 3;
  const int scol = ((tid & 7) ^ (srow & 7)) * 8;
  const unsigned short* Ab = A + (size_t)(bm * 256 + srow) * K + scol;
  const unsigned short* Wb = W + (size_t)(bn * 256 + srow) * K + scol;

#define STAGE_A(bufi, h, kt) do{ \
    async_cp16(Ab + (size_t)((h)*128     ) * K + (size_t)(kt) * 64, &lds[bufi][0][((h)*128     ) * 64 + tid * 8]); \
    async_cp16(Ab + (size_t)((h)*128 + 64) * K + (size_t)(kt) * 64, &lds[bufi][0][((h)*128 + 64) * 64 + tid * 8]); \
  }while(0)
#define STAGE_B(bufi, h, kt) do{ \
    async_cp16(Wb + (size_t)((h)*128     ) * K + (size_t)(kt) * 64, &lds[bufi][1][((h)*128     ) * 64 + tid * 8]); \
    async_cp16(Wb + (size_t)((h)*128 + 64) * K + (size_t)(kt) * 64, &lds[bufi][1][((h)*128 + 64) * 64 + tid * 8]); \
  }while(0)

  const int sw0 = ((qd    ) ^ (lr & 7)) * 8;
  const int sw1 = ((qd + 4) ^ (lr & 7)) * 8;
  const int arow = wm * 64 + lr;
  const int brow = wn * 32 + lr;

  bf16x8 af[4][2], b0[2][2], b1[2][2];

#define LDA(bufi, mh) do{ \
    _Pragma("unroll") \
    for (int mt = 0; mt < 4; ++mt){ \
      const int r_ = (mh)*128 + arow + mt * 16; \
      af[mt][0] = *(const bf16x8*)&lds[bufi][0][r_ * 64 + sw0]; \
      af[mt][1] = *(const bf16x8*)&lds[bufi][0][r_ * 64 + sw1]; \
    } }while(0)
#define LDB(bufi, nh, dst) do{ \
    _Pragma("unroll") \
    for (int nt = 0; nt < 2; ++nt){ \
      const int r_ = (nh)*128 + brow + nt * 16; \
      dst[nt][0] = *(const bf16x8*)&lds[bufi][1][r_ * 64 + sw0]; \
      dst[nt][1] = *(const bf16x8*)&lds[bufi][1][r_ * 64 + sw1]; \
    } }while(0)
#define MMA(mh, nh, bfr) do{ \
    __builtin_amdgcn_s_setprio(1); \
    _Pragma("unroll") \
    for (int kk = 0; kk < 2; ++kk) \
      _Pragma("unroll") \
      for (int mt = 0; mt < 4; ++mt) \
        _Pragma("unroll") \
        for (int nt = 0; nt < 2; ++nt) \
          acc[mh][nh][mt][nt] = __builtin_amdgcn_mfma_f32_16x16x32_bf16(af[mt][kk], bfr[nt][kk], acc[mh][nh][mt][nt], 0, 0, 0); \
    __builtin_amdgcn_s_setprio(0); \
  }while(0)

  STAGE_A(0, 0, 0); STAGE_B(0, 1, 0); STAGE_A(0, 1, 0); STAGE_B(0, 0, 0);
  STAGE_A(1, 0, 1); STAGE_B(1, 1, 1);
  VMW4(); BAR();

  for (int t = 0; t < NT; t += 2){
    const bool s2 = (t + 2) < NT, s3 = (t + 3) < NT;
    LDA(0, 0); LDB(0, 0, b0);
    STAGE_A(1, 1, t + 1);
    BAR(); MMA(0, 0, b0);
    LDB(0, 1, b1);
    BAR();
    STAGE_B(1, 0, t + 1);
    BAR(); MMA(0, 1, b1);
    LDA(0, 1);
    BAR();
    if (s2) STAGE_A(0, 0, t + 2);
    BAR(); MMA(1, 1, b1); BAR();
    if (s2) STAGE_B(0, 1, t + 2);
    BAR(); MMA(1, 0, b0);
    if (s2) { VMW4(); } else { VMW0(); }
    LDA(1, 0);
    BAR();
    LDB(1, 0, b0);
    if (s2) STAGE_A(0, 1, t + 2);
    BAR(); MMA(0, 0, b0);
    LDB(1, 1, b1);
    BAR();
    if (s2) STAGE_B(0, 0, t + 2);
    BAR(); MMA(0, 1, b1);
    LDA(1, 1);
    BAR();
    if (s3) STAGE_A(1, 0, t + 3);
    BAR(); MMA(1, 1, b1); BAR();
    if (s3) STAGE_B(1, 1, t + 3);
    BAR(); MMA(1, 0, b0);
    VMW4();
    BAR();
  }

  #pragma unroll
  for (int mh = 0; mh < 2; ++mh)
    #pragma unroll
    for (int nh = 0; nh < 2; ++nh)
      #pragma unroll
      for (int mt = 0; mt < 4; ++mt){
        const int gm0 = bm * 256 + mh * 128 + wm * 64 + mt * 16 + qd * 4;
        #pragma unroll
        for (int r = 0; r < 4; ++r){
          const size_t rowoff = (size_t)(gm0 + r) * N;
          #pragma unroll
          for (int nt = 0; nt < 2; ++nt){
            const int gn = bn * 256 + nh * 128 + wn * 32 + nt * 16 + lr;
            float v = acc[mh][nh][mt][nt][r] + bias[gn];
            if constexpr (EPI == 1) v = gelu_fast(v);
            outp[rowoff + gn] = f2bf(v);
          }
        }
      }
#undef STAGE_A
#undef STAGE_B
#undef LDA
#undef LDB
#undef MMA
}

// ---------------------------------------------------------------- GEMM 256x128, 4-phase early-read (Wo/FFN2, N=1024)
__global__ __launch_bounds__(512, 1) void gemm256x128(const unsigned short* __restrict__ A,
                                                      const unsigned short* __restrict__ W,
                                                      const float* __restrict__ bias,
                                                      const float* __restrict__ res,
                                                      float* __restrict__ outp,
                                                      int M, int N, int K){
  __shared__ unsigned short As[2][256 * 64];   // 64 KB
  __shared__ unsigned short Bs[2][128 * 64];   // 32 KB
  int bn, bm; xcd_swz(gridDim.x, gridDim.y, bn, bm);
  const int tid = threadIdx.x;
  const int lane = tid & 63;
  const int wv = tid >> 6;
  const int lr = lane & 15, qd = lane >> 4;
  const int wm = wv >> 1, wn = wv & 1;         // 4M x 2N
  const int NT = K >> 6;                       // even (K=1024/4096)

  f32x4 acc[4][4];
  #pragma unroll
  for (int a = 0; a < 4; ++a)
    #pragma unroll
    for (int b = 0; b < 4; ++b)
      acc[a][b] = f32x4{0.f, 0.f, 0.f, 0.f};

  const int srow = tid >> 3;                   // 0..63
  const int scol = ((tid & 7) ^ (srow & 7)) * 8;
  const int sdst = srow * 64 + (tid & 7) * 8;
  const unsigned short* Ab = A + (size_t)(bm * 256 + srow) * K + scol;
  const unsigned short* Wb = W + (size_t)(bn * 128 + srow) * K + scol;

#define XSTAGE_A(bufi, kt) do{ \
    _Pragma("unroll") \
    for (int h = 0; h < 4; ++h) \
      async_cp16(Ab + (size_t)(h * 64) * K + (size_t)(kt) * 64, &As[bufi][h * 64 * 64 + sdst]); \
  }while(0)
#define XSTAGE_B(bufi, kt) do{ \
    _Pragma("unroll") \
    for (int h = 0; h < 2; ++h) \
      async_cp16(Wb + (size_t)(h * 64) * K + (size_t)(kt) * 64, &Bs[bufi][h * 64 * 64 + sdst]); \
  }while(0)

  const int sw0 = ((qd    ) ^ (lr & 7)) * 8;
  const int sw1 = ((qd + 4) ^ (lr & 7)) * 8;
  const int arow = wm * 64 + lr;
  const int brow = wn * 64 + lr;

  bf16x8 af[4][2], b0[2][2], b1[2][2];

#define XLDA(bufi) do{ \
    _Pragma("unroll") \
    for (int mt = 0; mt < 4; ++mt){ \
      const int r_ = arow + mt * 16; \
      af[mt][0] = *(const bf16x8*)&As[bufi][r_ * 64 + sw0]; \
      af[mt][1] = *(const bf16x8*)&As[bufi][r_ * 64 + sw1]; \
    } }while(0)
#define XLDB0(bufi) do{ \
    _Pragma("unroll") \
    for (int j = 0; j < 2; ++j){ \
      const int r_ = brow + j * 16; \
      b0[j][0] = *(const bf16x8*)&Bs[bufi][r_ * 64 + sw0]; \
      b0[j][1] = *(const bf16x8*)&Bs[bufi][r_ * 64 + sw1]; \
    } }while(0)
#define XLDB1(bufi) do{ \
    _Pragma("unroll") \
    for (int j = 0; j < 2; ++j){ \
      const int r_ = brow + (2 + j) * 16; \
      b1[j][0] = *(const bf16x8*)&Bs[bufi][r_ * 64 + sw0]; \
      b1[j][1] = *(const bf16x8*)&Bs[bufi][r_ * 64 + sw1]; \
    } }while(0)
#define XMMA0() do{ \
    __builtin_amdgcn_s_setprio(1); \
    _Pragma("unroll") \
    for (int kk = 0; kk < 2; ++kk) \
      _Pragma("unroll") \
      for (int mt = 0; mt < 4; ++mt) \
        _Pragma("unroll") \
        for (int j = 0; j < 2; ++j) \
          acc[mt][j] = __builtin_amdgcn_mfma_f32_16x16x32_bf16(af[mt][kk], b0[j][kk], acc[mt][j], 0, 0, 0); \
    __builtin_amdgcn_s_setprio(0); \
  }while(0)
#define XMMA1() do{ \
    __builtin_amdgcn_s_setprio(1); \
    _Pragma("unroll") \
    for (int kk = 0; kk < 2; ++kk) \
      _Pragma("unroll") \
      for (int mt = 0; mt < 4; ++mt) \
        _Pragma("unroll") \
        for (int j = 0; j < 2; ++j) \
          acc[mt][2 + j] = __builtin_amdgcn_mfma_f32_16x16x32_bf16(af[mt][kk], b1[j][kk], acc[mt][2 + j], 0, 0, 0); \
    __builtin_amdgcn_s_setprio(0); \
  }while(0)

  XSTAGE_A(0, 0); XSTAGE_B(0, 0); XSTAGE_A(1, 1);
  VMW4(); BAR();

  for (int t = 0; t < NT; t += 2){
    const bool s2 = (t + 2) < NT;
    XLDA(0); XLDB0(0);
    XSTAGE_B(1, t + 1);
    BAR(); XMMA0();
    XLDB1(0);
    BAR();
    if (s2) XSTAGE_A(0, t + 2);
    BAR(); XMMA1();
    if (s2) { VMW4(); } else { VMW0(); }
    XLDA(1); XLDB0(1);
    BAR();
    if (s2) XSTAGE_B(0, t + 2);
    BAR(); XMMA0();
    XLDB1(1);
    BAR();
    if (s2) XSTAGE_A(1, t + 3);
    BAR(); XMMA1();
    if (s2) VMW4();
    BAR();
  }

  #pragma unroll
  for (int mt = 0; mt < 4; ++mt){
    #pragma unroll
    for (int r = 0; r < 4; ++r){
      const int gm = bm * 256 + wm * 64 + mt * 16 + qd * 4 + r;
      const size_t rowoff = (size_t)gm * N;
      #pragma unroll
      for (int nt = 0; nt < 4; ++nt){
        const int gn = bn * 128 + wn * 64 + nt * 16 + lr;
        const float v = acc[mt][nt][r] + bias[gn];
        outp[rowoff + gn] = v + res[rowoff + gn];
      }
    }
  }
#undef XSTAGE_A
#undef XSTAGE_B
#undef XLDA
#undef XLDB0
#undef XLDB1
#undef XMMA0
#undef XMMA1
}

// ---------------------------------------------------------------- V transpose: qkv[tok][2048+h*64+d] -> Vt[(b,h,d)][tok]
__global__ __launch_bounds__(256) void vtrans(const unsigned short* __restrict__ QKV,
                                              unsigned short* __restrict__ Vt){
  __shared__ unsigned short Ts[64 * 66];
  const int st = blockIdx.x;               // s-tile 0..31
  const int h = blockIdx.y, b = blockIdx.z;
  const int tid = threadIdx.x;
  const size_t srcbase = (size_t)(b * S_LEN + st * 64) * 3072 + 2 * E_DIM + h * HD;
  #pragma unroll
  for (int it = 0; it < 4; ++it){
    const int ch = tid + it * 256;
    const int row = ch >> 4, c4 = (ch & 15) * 4;
    *(ushort4*)&Ts[row * 66 + c4] = *(const ushort4*)(QKV + srcbase + (size_t)row * 3072 + c4);
  }
  __syncthreads();
  const size_t dstbase = (size_t)((b * NH + h) * HD) * S_LEN + st * 64;
  #pragma unroll
  for (int it = 0; it < 4; ++it){
    const int ch = tid + it * 256;
    const int d = ch >> 4, t4 = (ch & 15) * 4;
    ushort4 o;
    o.x = Ts[(t4 + 0) * 66 + d];
    o.y = Ts[(t4 + 1) * 66 + d];
    o.z = Ts[(t4 + 2) * 66 + d];
    o.w = Ts[(t4 + 3) * 66 + d];
    *(ushort4*)&Vt[dstbase + (size_t)d * S_LEN + t4] = o;
  }
}

// ---------------------------------------------------------------- MFMA flash attention, no-max softmax
// R9: QBLK=128 — each wave owns 32 q-rows (2 A-subtiles); kf/vf fragments are
// read ONCE per kk and reused by both subtiles, halving the K/V LDS re-read
// (attn is LDS-throughput-bound: ~89% LDS busy at R8). Grid (8,NH,NB)=512
// blocks = 2/CU; pair qt with 15-qt -> 34 KV-iterations/block (balanced).
// K/V staging, XOR-chunk layout, Ps convention, T14 prefetch all R7-proven.
#define AST 72   // Ps stride only
__global__ __launch_bounds__(256) void attn_mfma(const unsigned short* __restrict__ QKV,
                                                 const unsigned short* __restrict__ Vt,
                                                 unsigned short* __restrict__ Om){
  __shared__ unsigned short Ks[64 * 64];     // K[key][d], XOR-chunk layout
  __shared__ unsigned short Vs[64 * 64];     // V^T[d][key], XOR-chunk layout
  __shared__ unsigned short Ps[128 * AST];   // P[q][key], per-wave 32-row slices
  const int pairi = blockIdx.x;              // 0..7
  const int h = blockIdx.y, b = blockIdx.z;
  const int tid = threadIdx.x;
  const int w = tid >> 6, lane = tid & 63;
  const int lr = lane & 15, qd = lane >> 4;
  const size_t row0 = (size_t)b * S_LEN;
  const int qcol = h * HD;
  const int kcol = E_DIM + h * HD;
  const unsigned short* Vtb = Vt + (size_t)((b * NH + h) * HD) * S_LEN;

  const int sr  = tid >> 3;                         // 0..31
  const int sc  = (((tid & 7) ^ (sr & 7))) * 8;     // source col offset (ushorts)
  const int sdst = sr * 64 + (tid & 7) * 8;         // LDS dest (ushorts)

  bf16x8 ones;
  #pragma unroll
  for (int j = 0; j < 8; ++j) ones[j] = (__bf16)1.0f;

  for (int ph = 0; ph < 2; ++ph){
    const int qt = ph ? (15 - pairi) : pairi;   // 128-row q-tile index
    const int q0 = qt * 128 + w * 32;           // wave's first q-row
    const int nkt = 2 * qt + 2;                 // KV-tiles needed

    bf16x8 qf[2][2];
    #pragma unroll
    for (int qs = 0; qs < 2; ++qs)
      #pragma unroll
      for (int kk = 0; kk < 2; ++kk)
        qf[qs][kk] = *(const bf16x8*)(QKV + (row0 + q0 + qs * 16 + lr) * 3072 + qcol + kk * 32 + qd * 8);

    f32x4 accd[2][4];
    #pragma unroll
    for (int qs = 0; qs < 2; ++qs)
      #pragma unroll
      for (int dt = 0; dt < 4; ++dt) accd[qs][dt] = f32x4{0.f, 0.f, 0.f, 0.f};
    f32x4 lacc[2];
    lacc[0] = f32x4{0.f, 0.f, 0.f, 0.f};
    lacc[1] = f32x4{0.f, 0.f, 0.f, 0.f};

    // T14 prefetch tile 0
    uint4 k0r = *(const uint4*)(QKV + (row0 + sr) * 3072 + kcol + sc);
    uint4 k1r = *(const uint4*)(QKV + (row0 + sr + 32) * 3072 + kcol + sc);
    uint4 v0r = *(const uint4*)(Vtb + (size_t)sr * S_LEN + sc);
    uint4 v1r = *(const uint4*)(Vtb + (size_t)(sr + 32) * S_LEN + sc);

    for (int kt = 0; kt < nkt; ++kt){
      __syncthreads();
      *(uint4*)&Ks[sdst          ] = k0r;
      *(uint4*)&Ks[sdst + 32 * 64] = k1r;
      *(uint4*)&Vs[sdst          ] = v0r;
      *(uint4*)&Vs[sdst + 32 * 64] = v1r;
      if (kt + 1 < nkt){
        const int kn = kt + 1;
        k0r = *(const uint4*)(QKV + (row0 + kn * 64 + sr) * 3072 + kcol + sc);
        k1r = *(const uint4*)(QKV + (row0 + kn * 64 + sr + 32) * 3072 + kcol + sc);
        v0r = *(const uint4*)(Vtb + (size_t)sr * S_LEN + kn * 64 + sc);
        v1r = *(const uint4*)(Vtb + (size_t)(sr + 32) * S_LEN + kn * 64 + sc);
      }
      __syncthreads();

      // ---- QK^T (exp2 domain); kf shared across both q-subtiles
      f32x4 s[2][4];
      #pragma unroll
      for (int qs = 0; qs < 2; ++qs)
        #pragma unroll
        for (int nt = 0; nt < 4; ++nt) s[qs][nt] = f32x4{0.f, 0.f, 0.f, 0.f};
      #pragma unroll
      for (int kk = 0; kk < 2; ++kk){
        bf16x8 kf[4];
        #pragma unroll
        for (int nt = 0; nt < 4; ++nt)
          kf[nt] = *(const bf16x8*)&Ks[(nt * 16 + lr) * 64 + (((kk * 4 + qd) ^ (lr & 7))) * 8];
        #pragma unroll
        for (int qs = 0; qs < 2; ++qs)
          #pragma unroll
          for (int nt = 0; nt < 4; ++nt)
            s[qs][nt] = __builtin_amdgcn_mfma_f32_16x16x32_bf16(qf[qs][kk], kf[nt], s[qs][nt], 0, 0, 0);
      }
      // causal mask (exact per-subtile; only diagonal-overlapping tiles hit it)
      #pragma unroll
      for (int qs = 0; qs < 2; ++qs){
        if (kt * 64 + 63 > q0 + qs * 16){
          #pragma unroll
          for (int nt = 0; nt < 4; ++nt)
            #pragma unroll
            for (int r = 0; r < 4; ++r){
              const int q  = q0 + qs * 16 + qd * 4 + r;
              const int ky = kt * 64 + nt * 16 + lr;
              if (ky > q) s[qs][nt][r] = -3e38f;
            }
        }
      }
      // ---- p = exp2(s); pack into per-wave Ps slice
      #pragma unroll
      for (int qs = 0; qs < 2; ++qs)
        #pragma unroll
        for (int nt = 0; nt < 4; ++nt)
          #pragma unroll
          for (int r = 0; r < 4; ++r){
            union { float f; unsigned u; } cc;
            cc.f = exp2f(s[qs][nt][r]);
            Ps[(w * 32 + qs * 16 + qd * 4 + r) * AST + nt * 16 + lr] = (unsigned short)((cc.u + 0x8000u) >> 16);
          }
      __builtin_amdgcn_s_waitcnt(0xc07f);   // lgkmcnt(0): own P writes visible
      // ---- PV and l accumulation; vf shared across both q-subtiles
      #pragma unroll
      for (int kk = 0; kk < 2; ++kk){
        bf16x8 vf[4];
        #pragma unroll
        for (int dt = 0; dt < 4; ++dt)
          vf[dt] = *(const bf16x8*)&Vs[(dt * 16 + lr) * 64 + (((kk * 4 + qd) ^ (lr & 7))) * 8];
        #pragma unroll
        for (int qs = 0; qs < 2; ++qs){
          bf16x8 pf = *(const bf16x8*)&Ps[(w * 32 + qs * 16 + lr) * AST + kk * 32 + qd * 8];
          #pragma unroll
          for (int dt = 0; dt < 4; ++dt)
            accd[qs][dt] = __builtin_amdgcn_mfma_f32_16x16x32_bf16(pf, vf[dt], accd[qs][dt], 0, 0, 0);
          lacc[qs] = __builtin_amdgcn_mfma_f32_16x16x32_bf16(pf, ones, lacc[qs], 0, 0, 0);
        }
      }
    }

    // ---- epilogue: O = acc / l
    #pragma unroll
    for (int qs = 0; qs < 2; ++qs)
      #pragma unroll
      for (int r = 0; r < 4; ++r){
        const float inv = 1.0f / lacc[qs][r];
        const size_t ro = (row0 + q0 + qs * 16 + qd * 4 + r) * E_DIM + qcol;
        #pragma unroll
        for (int dt = 0; dt < 4; ++dt)
          Om[ro + dt * 16 + lr] = f2bf(accd[qs][dt][r] * inv);
      }
  }
}

// ---------------------------------------------------------------- launch
extern "C" void kernel_launch(void* const* d_in, const int* in_sizes, int n_in,
                              void* d_out, int out_size, void* d_ws, size_t ws_size,
                              hipStream_t stream){
  const float* x    = (const float*)d_in[0];
  const float* ln1g = (const float*)d_in[2];
  const float* ln1b = (const float*)d_in[3];
  const float* Wq   = (const float*)d_in[4];
  const float* bq   = (const float*)d_in[5];
  const float* Wk   = (const float*)d_in[6];
  const float* bk   = (const float*)d_in[7];
  const float* Wv   = (const float*)d_in[8];
  const float* bv   = (const float*)d_in[9];
  const float* Wo   = (const float*)d_in[10];
  const float* bo   = (const float*)d_in[11];
  const float* ln2g = (const float*)d_in[12];
  const float* ln2b = (const float*)d_in[13];
  const float* W1   = (const float*)d_in[14];
  const float* b1   = (const float*)d_in[15];
  const float* W2   = (const float*)d_in[16];
  const float* b2   = (const float*)d_in[17];

  char* ws = (char*)d_ws;
  const size_t MB = 1024 * 1024;
  unsigned short* Wqkv_b = (unsigned short*)(ws + 0 * MB);   // 6 MB (Wq|Wk|Wv)
  unsigned short* Wo_b   = (unsigned short*)(ws + 6 * MB);   // 2 MB
  unsigned short* W1_b   = (unsigned short*)(ws + 8 * MB);   // 8 MB
  unsigned short* W2_b   = (unsigned short*)(ws + 16 * MB);  // 8 MB
  unsigned short* qkvb   = (unsigned short*)(ws + 24 * MB);  // 48 MB [8192][3072]
  float*          bqkv   = (float*)(ws + 72 * MB);           // 12 KB (dead after QKV gemm)
  unsigned short* Vt_g   = (unsigned short*)(ws + 72 * MB);  // 16 MB (overwrites bqkv after use)
  unsigned short* lnb    = (unsigned short*)(ws + 88 * MB);  // 16 MB (ln out / attn ctx, reused)
  float*          xres   = (float*)(ws + 104 * MB);          // 32 MB
  unsigned short* ffn1   = (unsigned short*)(ws + 24 * MB);  // 64 MB, aliases qkvb+Vt (dead by then)
  unsigned short* ctxb   = lnb;                              // attn ctx shares lnb

  const float QSC = 0.125f * 1.4426950408889634f;            // 1/sqrt(D) * log2(e)

  // fused weight cvt + bias concat (was 7 launches)
  cvt_all<<<12300, 256, 0, stream>>>(Wq, Wk, Wv, Wo, W1, W2, bq, bk, bv,
                                     Wqkv_b, Wo_b, W1_b, W2_b, bqkv, QSC);

  ln_kernel<<<MROWS, 256, 0, stream>>>(x, ln1g, ln1b, lnb);

  // fused QKV GEMM: [8192,1024] @ [3072,1024]^T -> [8192,3072]  (256^2 early-read)
  gemm256<0><<<dim3(3 * E_DIM / 256, MROWS / 256), 512, 0, stream>>>(
      lnb, Wqkv_b, bqkv, qkvb, MROWS, 3 * E_DIM, E_DIM);

  vtrans<<<dim3(S_LEN / 64, NH, NB), 256, 0, stream>>>(qkvb, Vt_g);

  attn_mfma<<<dim3(8, NH, NB), 256, 0, stream>>>(qkvb, Vt_g, ctxb);

  // Wo: [8192,1024] @ [1024,1024]^T + x -> xres (fp32)  (256x128 4-phase)
  gemm256x128<<<dim3(E_DIM / 128, MROWS / 256), 512, 0, stream>>>(
      ctxb, Wo_b, bo, x, xres, MROWS, E_DIM, E_DIM);

  ln_kernel<<<MROWS, 256, 0, stream>>>(xres, ln2g, ln2b, lnb);

  // FFN1: [8192,1024] @ [4096,1024]^T -> gelu -> [8192,4096]  (256^2 early-read)
  gemm256<1><<<dim3(F_DIM / 256, MROWS / 256), 512, 0, stream>>>(
      lnb, W1_b, b1, ffn1, MROWS, F_DIM, E_DIM);

  // FFN2: [8192,4096] @ [1024,4096]^T + xres -> out (fp32)  (256x128 4-phase)
  gemm256x128<<<dim3(E_DIM / 128, MROWS / 256), 512, 0, stream>>>(
      ffn1, W2_b, b2, xres, (float*)d_out, MROWS, E_DIM, F_DIM);
}